// Round 2
// baseline (3041.785 us; speedup 1.0000x reference)
//
#include <hip/hip_runtime.h>
#include <math.h>

#define B_SZ 256
#define N_TOKENS 196
#define DIM 384
#define NH 8
#define KDIM 32
#define VDIM 128
#define QKV_ST 1536      // NH*(2*KDIM+VDIM)
#define HID 1536
#define CTX_ST 1024      // NH*VDIM
#define NOFF 196
#define CH 14            // 196 = 14 * 14 row chunks

// ---------------- GEMM: C[M][N] = A[M][K] @ B[N][K]^T + bias[N] ----------------
#define BM 64
#define BN 64
#define BK 16

__global__ __launch_bounds__(256)
void gemm_abT(const float* __restrict__ A, const float* __restrict__ Bm,
              const float* __restrict__ bias, float* __restrict__ C,
              int M, int N, int K) {
  __shared__ float As[BK][BM + 4];
  __shared__ float Bs[BK][BN + 4];
  const int tid = threadIdx.x;
  const int ntile = N / BN;
  const int bx = blockIdx.x % ntile;
  const int by = blockIdx.x / ntile;
  const int row0 = by * BM, col0 = bx * BN;

  const int lr = tid >> 2;          // 0..63: row (for A) / col (for B) within tile
  const int lk = (tid & 3) << 2;    // 0,4,8,12: k offset (float4)
  const float* Ap = A + (size_t)(row0 + lr) * K + lk;
  const float* Bp = Bm + (size_t)(col0 + lr) * K + lk;

  const int tx = tid & 15, ty = tid >> 4;
  float acc[4][4] = {};

  for (int k0 = 0; k0 < K; k0 += BK) {
    float4 av = *(const float4*)(Ap + k0);
    float4 bv = *(const float4*)(Bp + k0);
    __syncthreads();
    As[lk + 0][lr] = av.x; As[lk + 1][lr] = av.y;
    As[lk + 2][lr] = av.z; As[lk + 3][lr] = av.w;
    Bs[lk + 0][lr] = bv.x; Bs[lk + 1][lr] = bv.y;
    Bs[lk + 2][lr] = bv.z; Bs[lk + 3][lr] = bv.w;
    __syncthreads();
#pragma unroll
    for (int kk = 0; kk < BK; ++kk) {
      float4 a = *(const float4*)&As[kk][ty << 2];
      float4 b = *(const float4*)&Bs[kk][tx << 2];
      float ar[4] = {a.x, a.y, a.z, a.w};
      float br[4] = {b.x, b.y, b.z, b.w};
#pragma unroll
      for (int i = 0; i < 4; ++i)
#pragma unroll
        for (int j = 0; j < 4; ++j)
          acc[i][j] += ar[i] * br[j];
    }
  }
#pragma unroll
  for (int i = 0; i < 4; ++i) {
    const int row = row0 + (ty << 2) + i;
    const int col = col0 + (tx << 2);
    float4 o;
    o.x = acc[i][0] + bias[col + 0];
    o.y = acc[i][1] + bias[col + 1];
    o.z = acc[i][2] + bias[col + 2];
    o.w = acc[i][3] + bias[col + 3];
    *(float4*)&C[(size_t)row * N + col] = o;
  }
}

// ---------------- Fused attention: one block per (b,h) within slice ----------------
// qkv layout per token: [H][192] = q(32) k(32) v(128). ctx layout: (Bs,N,H,128).
__global__ __launch_bounds__(256)
void attn_fused(const float* __restrict__ qkv, const float* __restrict__ ab_table,
                const int* __restrict__ bias_idxs, float* __restrict__ ctx) {
  __shared__ float q_s[N_TOKENS][KDIM];    // broadcast reads only -> no pad
  __shared__ float p_s[N_TOKENS][20];      // 14 rows of P per m, padded (bank stride 20)
  __shared__ float part_s[VDIM][15];       // half-1 context partials
  __shared__ float redmax_s[CH][4];
  __shared__ float redsum_s[CH][4];

  const int bh = blockIdx.x;
  const int b = bh >> 3, h = bh & 7;       // b is slice-local
  const int tid = threadIdx.x;
  const int lane = tid & 63, wave = tid >> 6;
  const int m = tid;
  const bool valid = m < N_TOKENS;

  const float* base = qkv + (size_t)b * N_TOKENS * QKV_ST + h * 192;

  // stage q into LDS
  for (int i = tid; i < N_TOKENS * 8; i += 256) {
    int mm = i >> 3, kq = (i & 7) << 2;
    *(float4*)&q_s[mm][kq] = *(const float4*)(base + (size_t)mm * QKV_ST + kq);
  }

  // k row for this thread's m into registers
  float k_reg[KDIM];
  if (valid) {
#pragma unroll
    for (int kq = 0; kq < 8; ++kq) {
      float4 kv = *(const float4*)(base + (size_t)m * QKV_ST + KDIM + (kq << 2));
      k_reg[kq * 4 + 0] = kv.x; k_reg[kq * 4 + 1] = kv.y;
      k_reg[kq * 4 + 2] = kv.z; k_reg[kq * 4 + 3] = kv.w;
    }
  } else {
#pragma unroll
    for (int i = 0; i < KDIM; ++i) k_reg[i] = 0.f;
  }
  __syncthreads();

  const float scale = 0.17677669529663687f;   // 32^-0.5
  const int d = tid & (VDIM - 1);
  const int half = tid >> 7;
  const float* vp0 = base + 2 * KDIM + (size_t)half * 98 * QKV_ST + d;
  const float* abh = ab_table + h * NOFF;

#pragma unroll 1
  for (int c = 0; c < N_TOKENS / CH; ++c) {
    const int n0 = c * CH;
    float ev[CH];

    // ---- S rows: thread m computes S[n0+r][m] ----
#pragma unroll
    for (int r = 0; r < CH; ++r) {
      float acc = 0.f;
#pragma unroll
      for (int kq = 0; kq < 8; ++kq) {
        float4 qv = *(const float4*)&q_s[n0 + r][kq << 2];  // wave-uniform broadcast
        acc += qv.x * k_reg[kq * 4 + 0] + qv.y * k_reg[kq * 4 + 1]
             + qv.z * k_reg[kq * 4 + 2] + qv.w * k_reg[kq * 4 + 3];
      }
      float sv = -INFINITY;
      if (valid) sv = acc * scale + abh[bias_idxs[(n0 + r) * N_TOKENS + m]];
      ev[r] = sv;
    }

    // ---- row max ----
#pragma unroll
    for (int r = 0; r < CH; ++r) {
      float v = ev[r];
#pragma unroll
      for (int off = 32; off > 0; off >>= 1)
        v = fmaxf(v, __shfl_xor(v, off));
      if (lane == 0) redmax_s[r][wave] = v;
    }
    __syncthreads();  // (A)

#pragma unroll
    for (int r = 0; r < CH; ++r) {
      float mx = fmaxf(fmaxf(redmax_s[r][0], redmax_s[r][1]),
                       fmaxf(redmax_s[r][2], redmax_s[r][3]));
      ev[r] = valid ? __expf(ev[r] - mx) : 0.f;
    }

    // ---- row sum ----
#pragma unroll
    for (int r = 0; r < CH; ++r) {
      float v = ev[r];
#pragma unroll
      for (int off = 32; off > 0; off >>= 1)
        v += __shfl_xor(v, off);
      if (lane == 0) redsum_s[r][wave] = v;
    }
    if (valid) {
      float4* pm = (float4*)&p_s[m][0];
      pm[0] = make_float4(ev[0], ev[1], ev[2], ev[3]);
      pm[1] = make_float4(ev[4], ev[5], ev[6], ev[7]);
      pm[2] = make_float4(ev[8], ev[9], ev[10], ev[11]);
      pm[3] = make_float4(ev[12], ev[13], 0.f, 0.f);
    }
    __syncthreads();  // (B)

    float inv[CH];
#pragma unroll
    for (int r = 0; r < CH; ++r)
      inv[r] = 1.f / (redsum_s[r][0] + redsum_s[r][1] +
                      redsum_s[r][2] + redsum_s[r][3]);

    // ---- context ----
    float cacc[CH] = {};
#pragma unroll 4
    for (int mm = 0; mm < 98; ++mm) {
      float vv = vp0[(size_t)mm * QKV_ST];
      const float4* pr = (const float4*)&p_s[half * 98 + mm][0];
      float4 pa = pr[0], pb = pr[1], pc = pr[2], pd = pr[3];
      cacc[0]  += pa.x * vv;  cacc[1]  += pa.y * vv;
      cacc[2]  += pa.z * vv;  cacc[3]  += pa.w * vv;
      cacc[4]  += pb.x * vv;  cacc[5]  += pb.y * vv;
      cacc[6]  += pb.z * vv;  cacc[7]  += pb.w * vv;
      cacc[8]  += pc.x * vv;  cacc[9]  += pc.y * vv;
      cacc[10] += pc.z * vv;  cacc[11] += pc.w * vv;
      cacc[12] += pd.x * vv;  cacc[13] += pd.y * vv;
    }
    if (half == 1) {
#pragma unroll
      for (int r = 0; r < CH; ++r) part_s[d][r] = cacc[r];
    }
    __syncthreads();  // (C)
    if (half == 0) {
      float* cp = ctx + (((size_t)b * N_TOKENS + n0) * NH + h) * VDIM + d;
#pragma unroll
      for (int r = 0; r < CH; ++r)
        cp[(size_t)r * NH * VDIM] = (cacc[r] + part_s[d][r]) * inv[r];
    }
  }
}

extern "C" void kernel_launch(void* const* d_in, const int* in_sizes, int n_in,
                              void* d_out, int out_size, void* d_ws, size_t ws_size,
                              hipStream_t stream) {
  const float* x     = (const float*)d_in[0];
  const float* Wqkv  = (const float*)d_in[1];
  const float* bqkv  = (const float*)d_in[2];
  const float* Wproj = (const float*)d_in[3];
  const float* bproj = (const float*)d_in[4];
  const float* ab    = (const float*)d_in[5];
  const int*   bidx  = (const int*)d_in[6];
  float* out = (float*)d_out;

  // Per-batch-element scratch: qkv row (196x1536 f32) + ctx row (196x1024 f32)
  const size_t per_b = (size_t)N_TOKENS * (QKV_ST + CTX_ST) * sizeof(float); // ~2.0 MB
  // Largest power-of-two slice that fits ws_size; Bs>=16 keeps M % 64 == 0.
  int Bs = B_SZ;
  while (Bs > 16 && (size_t)Bs * per_b > ws_size) Bs >>= 1;

  float* qkv_s = (float*)d_ws;                                  // Bs x 196 x 1536
  float* ctx_s = qkv_s + (size_t)Bs * N_TOKENS * QKV_ST;        // Bs x 196 x 1024

  const int nslice = B_SZ / Bs;
  const int Ms = Bs * N_TOKENS;   // rows per slice (divisible by 64 for Bs>=16)

  for (int s = 0; s < nslice; ++s) {
    const float* xs   = x   + (size_t)s * Bs * N_TOKENS * DIM;
    float*       outs = out + (size_t)s * Bs * N_TOKENS * DIM;

    // 1) qkv = x @ Wqkv^T + bqkv
    gemm_abT<<<dim3((Ms / BM) * (HID / BN)), dim3(256), 0, stream>>>(
        xs, Wqkv, bqkv, qkv_s, Ms, HID, DIM);
    // 2) fused bias+softmax attention -> ctx (Bs,N,H*128)
    attn_fused<<<dim3(Bs * NH), dim3(256), 0, stream>>>(qkv_s, ab, bidx, ctx_s);
    // 3) out = ctx @ Wproj^T + bproj
    gemm_abT<<<dim3((Ms / BM) * (DIM / BN)), dim3(256), 0, stream>>>(
        ctx_s, Wproj, bproj, outs, Ms, DIM, CTX_ST);
  }
}

// Round 3
// 587.440 us; speedup vs baseline: 5.1780x; 5.1780x over previous
//
#include <hip/hip_runtime.h>
#include <math.h>

#define B_SZ 256
#define N_TOKENS 196
#define DIM 384
#define NH 8
#define QKV_ST 1536      // NH*(2*32+128)
#define HID 1536
#define CTX_ST 1024      // NH*128
#define VT_ST 208        // padded token stride of V^T (13*16)

typedef short s16x8_base __attribute__((ext_vector_type(8)));
typedef s16x8_base __attribute__((may_alias)) s16x8;
typedef float f32x4_base __attribute__((ext_vector_type(4)));
typedef f32x4_base __attribute__((may_alias)) f32x4;

__device__ inline unsigned short f2b(float f) {
  union { float f; unsigned int u; } v; v.f = f;
  unsigned int r = (v.u + 0x7FFFu + ((v.u >> 16) & 1u)) >> 16;   // RNE, finite inputs
  return (unsigned short)r;
}

// ---------------- fp32 -> bf16 convert (vectorized, grid-stride) ----------------
__global__ __launch_bounds__(256)
void cvt_f32_bf16(const float* __restrict__ in, unsigned short* __restrict__ out, int n4) {
  int i = blockIdx.x * 256 + threadIdx.x;
  const int stride = gridDim.x * 256;
  for (; i < n4; i += stride) {
    float4 v = ((const float4*)in)[i];
    ushort4 o;
    o.x = f2b(v.x); o.y = f2b(v.y); o.z = f2b(v.z); o.w = f2b(v.w);
    ((ushort4*)out)[i] = o;
  }
}

// ---------------- bf16 MFMA GEMM: C[M][N] = A[M][K] @ B[N][K]^T + bias ----------------
// 128x128 tile, BK=32, 256 threads, wave-tile 64x64 (4x4 of 16x16x32).
template <int OUT_BF16>
__global__ __launch_bounds__(256)
void gemm_bf16_bt(const unsigned short* __restrict__ A,
                  const unsigned short* __restrict__ Bm,
                  const float* __restrict__ bias,
                  void* __restrict__ C, int M, int N, int K) {
  __shared__ unsigned short As[128][32];
  __shared__ unsigned short Bs[128][32];
  const int tid = threadIdx.x;
  const int lane = tid & 63, wave = tid >> 6;
  const int quad = lane >> 4, l15 = lane & 15;
  const int ntile = N >> 7;
  const int bx = blockIdx.x % ntile, by = blockIdx.x / ntile;
  const int row0 = by << 7, col0 = bx << 7;

  const int srow = tid >> 1, soff = (tid & 1) << 4;   // staging: 32B per thread
  const unsigned short* Ag = A + (size_t)(row0 + srow) * K + soff;
  const unsigned short* Bg = Bm + (size_t)(col0 + srow) * K + soff;

  const int wr = (wave >> 1) << 6, wc = (wave & 1) << 6;

  f32x4 zero = {0.f, 0.f, 0.f, 0.f};
  f32x4 acc[4][4];
#pragma unroll
  for (int i = 0; i < 4; ++i)
#pragma unroll
    for (int j = 0; j < 4; ++j) acc[i][j] = zero;

  s16x8 a0 = *(const s16x8*)(Ag + 0);
  s16x8 a1 = *(const s16x8*)(Ag + 8);
  s16x8 b0 = *(const s16x8*)(Bg + 0);
  s16x8 b1 = *(const s16x8*)(Bg + 8);

  for (int k0 = 0; k0 < K; k0 += 32) {
    __syncthreads();
    *(s16x8*)&As[srow][soff] = a0;
    *(s16x8*)&As[srow][soff + 8] = a1;
    *(s16x8*)&Bs[srow][soff] = b0;
    *(s16x8*)&Bs[srow][soff + 8] = b1;
    __syncthreads();
    if (k0 + 32 < K) {
      a0 = *(const s16x8*)(Ag + k0 + 32);
      a1 = *(const s16x8*)(Ag + k0 + 40);
      b0 = *(const s16x8*)(Bg + k0 + 32);
      b1 = *(const s16x8*)(Bg + k0 + 40);
    }
    s16x8 af[4], bf[4];
#pragma unroll
    for (int i = 0; i < 4; ++i) {
      af[i] = *(const s16x8*)&As[wr + i * 16 + l15][quad * 8];
      bf[i] = *(const s16x8*)&Bs[wc + i * 16 + l15][quad * 8];
    }
#pragma unroll
    for (int i = 0; i < 4; ++i)
#pragma unroll
      for (int j = 0; j < 4; ++j)
        acc[i][j] = __builtin_amdgcn_mfma_f32_16x16x32_bf16(af[i], bf[j], acc[i][j], 0, 0, 0);
  }

#pragma unroll
  for (int j = 0; j < 4; ++j) {
    const int col = col0 + wc + j * 16 + l15;
    const float bj = bias[col];
#pragma unroll
    for (int i = 0; i < 4; ++i) {
      const int rowb = row0 + wr + i * 16 + quad * 4;
#pragma unroll
      for (int r = 0; r < 4; ++r) {
        float v = acc[i][j][r] + bj;
        if (OUT_BF16)
          ((unsigned short*)C)[(size_t)(rowb + r) * N + col] = f2b(v);
        else
          ((float*)C)[(size_t)(rowb + r) * N + col] = v;
      }
    }
  }
}

// ---------------- V -> V^T (per (b,h): [196][128] -> [128][208]) ----------------
// grid: bh*28 blocks; one 32x32 tile each. Pad tokens 196..207 written as 0.
__global__ __launch_bounds__(256)
void transpose_v(const unsigned short* __restrict__ qkv, unsigned short* __restrict__ vt) {
  __shared__ unsigned short ts[32][36];
  const int id = blockIdx.x;
  const int tile = id % 28;
  const int bh = id / 28;
  const int b = bh >> 3, h = bh & 7;
  const int nt = tile % 7, dt = tile / 7;
  const int n0 = nt * 32, d0 = dt * 32;
  const int t = threadIdx.x;
  {
    const int nl = t >> 3, dq = (t & 7) << 2;
    ushort4 v4; v4.x = 0; v4.y = 0; v4.z = 0; v4.w = 0;
    if (n0 + nl < 196)
      v4 = *(const ushort4*)(qkv + ((size_t)(b * 196 + n0 + nl) * QKV_ST + h * 192 + 64 + d0 + dq));
    ts[dq + 0][nl] = v4.x; ts[dq + 1][nl] = v4.y;
    ts[dq + 2][nl] = v4.z; ts[dq + 3][nl] = v4.w;
  }
  __syncthreads();
  {
    const int dl = t >> 3, nq = (t & 7) << 2;
    if (n0 + nq < VT_ST) {
      ushort4 o;
      o.x = ts[dl][nq + 0]; o.y = ts[dl][nq + 1];
      o.z = ts[dl][nq + 2]; o.w = ts[dl][nq + 3];
      *(ushort4*)(vt + ((size_t)(bh * 128 + d0 + dl) * VT_ST + n0 + nq)) = o;
    }
  }
}

// ---------------- MFMA attention: one block per (b,h) ----------------
// S = qk^T*scale + bias (q/k frags direct from global), wave-local softmax,
// P (bf16) in LDS, PV via MFMA against LDS-staged V^T tiles.
__global__ __launch_bounds__(256)
void attn_mfma(const unsigned short* __restrict__ qkv,
               const unsigned short* __restrict__ vt,
               const float* __restrict__ ab, const int* __restrict__ bidx,
               unsigned short* __restrict__ ctx) {
  __shared__ unsigned short Pm[112][232];   // P chunk: 112 rows, stride 232 (16B-aligned, 2-way banks)
  __shared__ unsigned short vts[128][32];   // V^T k-tile
  __shared__ float inv_s[112];

  const int bh = blockIdx.x;
  const int b = bh >> 3, h = bh & 7;
  const int tid = threadIdx.x;
  const int lane = tid & 63, w = tid >> 6;
  const int quad = lane >> 4, l15 = lane & 15;
  const float scale = 0.17677669529663687f;

  const unsigned short* qbase = qkv + (size_t)b * N_TOKENS * QKV_ST + h * 192;
  const unsigned short* vbase = vt + (size_t)bh * 128 * VT_ST;
  const float* abh = ab + h * 196;

  if (tid < 112) {
#pragma unroll
    for (int c = 208; c < 232; ++c) Pm[tid][c] = 0;   // zero mm-pad so pad cols contribute 0
  }

  const int srow = tid >> 1, soff = (tid & 1) << 4;   // V^T staging: 32B/thread
  const unsigned short* vg = vbase + (size_t)srow * VT_ST + soff;

  f32x4 zero = {0.f, 0.f, 0.f, 0.f};

  for (int chunk = 0; chunk < 2; ++chunk) {
    const int nbase = chunk * 112;
    __syncthreads();   // Pm/inv_s free (prev chunk done); pad-zero visible

    // ---- S phase: wave w owns local tile-rows {2w, 2w+1} (wave 3: one) ----
    const int ntr = (w < 3) ? 2 : 1;
    for (int t2 = 0; t2 < ntr; ++t2) {
      const int rowt = w * 32 + t2 * 16;
      s16x8 aq = *(const s16x8*)(qbase + (size_t)(nbase + rowt + l15) * QKV_ST + quad * 8);
      f32x4 sacc[13];
#pragma unroll
      for (int j = 0; j < 13; ++j) {
        s16x8 bk = *(const s16x8*)(qbase + (size_t)(j * 16 + l15) * QKV_ST + 32 + quad * 8);
        sacc[j] = __builtin_amdgcn_mfma_f32_16x16x32_bf16(aq, bk, zero, 0, 0, 0);
      }
      float mx[4] = {-1e30f, -1e30f, -1e30f, -1e30f};
#pragma unroll
      for (int j = 0; j < 13; ++j) {
        const int m = j * 16 + l15;
        const int mc = m < 196 ? m : 195;
#pragma unroll
        for (int r = 0; r < 4; ++r) {
          const int n = nbase + rowt + quad * 4 + r;
          const int nc = n < 196 ? n : 195;
          float s = sacc[j][r] * scale + abh[bidx[nc * 196 + mc]];
          s = (m < 196) ? s : -1e30f;
          sacc[j][r] = s;
          mx[r] = fmaxf(mx[r], s);
        }
      }
#pragma unroll
      for (int o = 8; o > 0; o >>= 1)
#pragma unroll
        for (int r = 0; r < 4; ++r) mx[r] = fmaxf(mx[r], __shfl_xor(mx[r], o));
      float sm[4] = {0.f, 0.f, 0.f, 0.f};
#pragma unroll
      for (int j = 0; j < 13; ++j)
#pragma unroll
        for (int r = 0; r < 4; ++r) {
          float e = __expf(sacc[j][r] - mx[r]);
          sm[r] += e;
          Pm[rowt + quad * 4 + r][j * 16 + l15] = f2b(e);
        }
#pragma unroll
      for (int o = 8; o > 0; o >>= 1)
#pragma unroll
        for (int r = 0; r < 4; ++r) sm[r] += __shfl_xor(sm[r], o);
      if (l15 == 0) {
#pragma unroll
        for (int r = 0; r < 4; ++r) inv_s[rowt + quad * 4 + r] = 1.f / sm[r];
      }
    }

    // ---- PV: wave w owns d-cols [w*32, w*32+32); 7 row-tiles x 2 col-tiles ----
    f32x4 pacc[7][2];
#pragma unroll
    for (int i = 0; i < 7; ++i) { pacc[i][0] = zero; pacc[i][1] = zero; }

    s16x8 v0 = *(const s16x8*)(vg + 0);
    s16x8 v1 = *(const s16x8*)(vg + 8);
    for (int ks = 0; ks < 7; ++ks) {
      __syncthreads();   // P/inv visible (ks=0); prev vts reads done
      *(s16x8*)&vts[srow][soff] = v0;
      *(s16x8*)&vts[srow][soff + 8] = v1;
      __syncthreads();   // vts ready
      if (ks < 6) {
        v0 = *(const s16x8*)(vg + (ks + 1) * 32);
        v1 = *(const s16x8*)(vg + (ks + 1) * 32 + 8);
      }
      s16x8 bf0 = *(const s16x8*)&vts[w * 32 + l15][quad * 8];
      s16x8 bf1 = *(const s16x8*)&vts[w * 32 + 16 + l15][quad * 8];
#pragma unroll
      for (int i = 0; i < 7; ++i) {
        s16x8 ap = *(const s16x8*)&Pm[i * 16 + l15][ks * 32 + quad * 8];
        pacc[i][0] = __builtin_amdgcn_mfma_f32_16x16x32_bf16(ap, bf0, pacc[i][0], 0, 0, 0);
        pacc[i][1] = __builtin_amdgcn_mfma_f32_16x16x32_bf16(ap, bf1, pacc[i][1], 0, 0, 0);
      }
    }

    // ---- epilogue: normalize + store (bf16 ctx) ----
#pragma unroll
    for (int i = 0; i < 7; ++i) {
#pragma unroll
      for (int jl = 0; jl < 2; ++jl) {
        const int d = w * 32 + jl * 16 + l15;
#pragma unroll
        for (int r = 0; r < 4; ++r) {
          const int nl = i * 16 + quad * 4 + r;
          const int n = nbase + nl;
          if (n < 196) {
            float v = pacc[i][jl][r] * inv_s[nl];
            ctx[(size_t)(b * N_TOKENS + n) * CTX_ST + h * 128 + d] = f2b(v);
          }
        }
      }
    }
  }
}

extern "C" void kernel_launch(void* const* d_in, const int* in_sizes, int n_in,
                              void* d_out, int out_size, void* d_ws, size_t ws_size,
                              hipStream_t stream) {
  const float* x     = (const float*)d_in[0];
  const float* Wqkv  = (const float*)d_in[1];
  const float* bqkv  = (const float*)d_in[2];
  const float* Wproj = (const float*)d_in[3];
  const float* bproj = (const float*)d_in[4];
  const float* ab    = (const float*)d_in[5];
  const int*   bidx  = (const int*)d_in[6];
  float* out = (float*)d_out;

  const size_t szWq = 589824, szWp = 393216, szX = (size_t)B_SZ * N_TOKENS * DIM;
  const size_t fixedB = (szWq + szWp + szX) * 2;
  // per-batch: vt 8*128*208 + qkv 196*1536 + ctx 196*1024 elements (bf16)
  const size_t perB = (212992ULL + 301056ULL + 200704ULL) * 2;
  int Bs = 256;
  while (Bs > 32 && fixedB + (size_t)Bs * perB > ws_size) Bs >>= 1;

  unsigned short* Wqb  = (unsigned short*)d_ws;
  unsigned short* Wpb  = Wqb + szWq;
  unsigned short* xb   = Wpb + szWp;
  unsigned short* vtb  = xb + szX;
  unsigned short* qkvb = vtb + (size_t)Bs * 212992;
  unsigned short* ctxb = qkvb + (size_t)Bs * 301056;

  cvt_f32_bf16<<<dim3(576), dim3(256), 0, stream>>>(Wqkv, Wqb, (int)(szWq / 4));
  cvt_f32_bf16<<<dim3(384), dim3(256), 0, stream>>>(Wproj, Wpb, (int)(szWp / 4));
  cvt_f32_bf16<<<dim3(4096), dim3(256), 0, stream>>>(x, xb, (int)(szX / 4));

  const int nslice = B_SZ / Bs;
  const int Ms = Bs * N_TOKENS;
  for (int s = 0; s < nslice; ++s) {
    const unsigned short* xs = xb + (size_t)s * Ms * DIM;
    float* outs = out + (size_t)s * Ms * DIM;
    gemm_bf16_bt<1><<<dim3((Ms / 128) * (HID / 128)), dim3(256), 0, stream>>>(
        xs, Wqb, bqkv, qkvb, Ms, HID, DIM);
    transpose_v<<<dim3(Bs * 8 * 28), dim3(256), 0, stream>>>(qkvb, vtb);
    attn_mfma<<<dim3(Bs * 8), dim3(256), 0, stream>>>(qkvb, vtb, ab, bidx, ctxb);
    gemm_bf16_bt<0><<<dim3((Ms / 128) * (DIM / 128)), dim3(256), 0, stream>>>(
        ctxb, Wpb, bproj, outs, Ms, DIM, CTX_ST);
  }
}